// Round 4
// baseline (149.994 us; speedup 1.0000x reference)
//
#include <hip/hip_runtime.h>
#include <hip/hip_bf16.h>
#include <math.h>

typedef short bf16x8 __attribute__((ext_vector_type(8)));
typedef float f32x4 __attribute__((ext_vector_type(4)));

#define B_HALF 2048
#define N_TOT  4096
#define D_DIM  128
#define K_DIM  512
#define BK     64
#define NGRP   32
#define NBLK   528   // triangular 32x32 tile grid

// ---------------------------------------------------------------------------
// Self-cleaning software grid barrier.
// g_bar is zero-initialized at module load. Last arriver (v == grid-1)
// resets the counter to 0 (release). Spinners pass on v==0 or v>=grid:
// after a thread's own RMW, per-location coherence means any observed 0
// can only be the post-completion reset -> safe, and the counter is left
// at 0 for the next call (deterministic across graph replays).
// ---------------------------------------------------------------------------
__device__ unsigned g_bar[4];

__device__ __forceinline__ void grid_barrier(int k) {
  __syncthreads();
  if (threadIdx.x == 0) {
    unsigned v = __hip_atomic_fetch_add(&g_bar[k], 1u, __ATOMIC_ACQ_REL,
                                        __HIP_MEMORY_SCOPE_AGENT);
    if (v == gridDim.x - 1) {
      __hip_atomic_store(&g_bar[k], 0u, __ATOMIC_RELEASE,
                         __HIP_MEMORY_SCOPE_AGENT);
    } else {
      unsigned w;
      do {
        __builtin_amdgcn_s_sleep(2);
        w = __hip_atomic_load(&g_bar[k], __ATOMIC_ACQUIRE,
                              __HIP_MEMORY_SCOPE_AGENT);
      } while (w != 0u && w < gridDim.x);
    }
  }
  __syncthreads();
}

#define GLOAD16(src, dst)                                                     \
  __builtin_amdgcn_global_load_lds(                                           \
      (const __attribute__((address_space(1))) void*)(src),                   \
      (__attribute__((address_space(3))) void*)(dst), 16, 0, 0)

// ---------------------------------------------------------------------------
// Single fused kernel:
//   P0: bf16 features (L,R) + a[]           (grid-stride over 4096 rows)
//   P1: triangular 128x128 MFMA tiles + fused two-sided LSE partials
//   P2: per-row LSE combine -> 512 block partials
//   P3: block 0 final sum -> out
// ---------------------------------------------------------------------------
__global__ __launch_bounds__(256, 3) void fused_all(
    const float* __restrict__ mu_x, const float* __restrict__ sigma_x,
    const float* __restrict__ mu_p, const float* __restrict__ sigma_p,
    __hip_bfloat16* __restrict__ Lf, __hip_bfloat16* __restrict__ Rf,
    float* __restrict__ a, float* __restrict__ lsep, float* __restrict__ pos,
    float* __restrict__ partial, float* __restrict__ out, float to_add) {
  __shared__ char lt[128 * BK * 2];   // 16 KB
  __shared__ char rt[128 * BK * 2];   // 16 KB
  __shared__ float2 red[128][2];      // 2 KB
  __shared__ float wsum[4];
  __shared__ float rp8[8];
  __shared__ float fr[256];           // 1 KB

  const int tid = threadIdx.x;
  const int bid = blockIdx.x;

  // =========== P0: feature prep (2 rows per block-pass) ===========
  for (int r0 = bid * 2; r0 < N_TOT; r0 += NBLK * 2) {
    int row = r0 + (tid >> 7);
    int d   = tid & 127;
    const float* mup = (row < B_HALF) ? mu_x : mu_p;
    const float* sgp = (row < B_HALF) ? sigma_x : sigma_p;
    int gi = row & (B_HALF - 1);
    float mu  = mup[gi * D_DIM + d];
    float sg  = sgp[gi * D_DIM + d];
    float var = sg * sg;
    float inv = 1.0f / var;
    float vm  = var + mu * mu;
    size_t base = (size_t)row * K_DIM;
    Lf[base + d]       = __float2bfloat16(inv);
    Lf[base + 128 + d] = __float2bfloat16(vm);
    Lf[base + 256 + d] = __float2bfloat16(mu * inv);
    Lf[base + 384 + d] = __float2bfloat16(mu);
    Rf[base + d]       = __float2bfloat16(vm);
    Rf[base + 128 + d] = __float2bfloat16(inv);
    Rf[base + 256 + d] = __float2bfloat16(-2.0f * mu);
    Rf[base + 384 + d] = __float2bfloat16(-2.0f * mu * inv);

    float v = mu * mu * inv;
#pragma unroll
    for (int x = 1; x < 64; x <<= 1) v += __shfl_xor(v, x);
    if ((tid & 63) == 0) wsum[tid >> 6] = v;
    __syncthreads();
    if ((tid & 127) == 0) a[row] = wsum[tid >> 6] + wsum[(tid >> 6) + 1];
    __syncthreads();
  }

  grid_barrier(0);

  // =========== P1: triangular tile GEMM + epilogue ===========
  {
    int t = bid;
    int rb = 0;
    while (t >= 32 - rb) { t -= 32 - rb; ++rb; }
    const int cb = rb + t;

    const int lane = tid & 63;
    const int wave = tid >> 6;
    const int rowBase = rb * 128, colBase = cb * 128;
    const int wr = wave >> 1, wc = wave & 1;
    const int lx = lane & 15;
    const int rq = lane >> 4;

    f32x4 acc[4][4];
#pragma unroll
    for (int m = 0; m < 4; ++m)
#pragma unroll
      for (int n = 0; n < 4; ++n) acc[m][n] = (f32x4){0.f, 0.f, 0.f, 0.f};

    const int ric   = lane >> 3;
    const int cbyte = ((lane & 7) * 16) ^ (ric << 4);
    const int swzk  = (lane & 7) << 4;

    for (int kk = 0; kk < K_DIM / BK; ++kk) {
      const char* lsrc = (const char*)Lf + (size_t)rowBase * (K_DIM * 2) + kk * (BK * 2);
      const char* rsrc = (const char*)Rf + (size_t)colBase * (K_DIM * 2) + kk * (BK * 2);
#pragma unroll
      for (int t4 = 0; t4 < 4; ++t4) {
        int chunk = wave * 4 + t4;
        GLOAD16(lsrc + (size_t)(chunk * 8 + ric) * (K_DIM * 2) + cbyte, lt + chunk * 1024);
        GLOAD16(rsrc + (size_t)(chunk * 8 + ric) * (K_DIM * 2) + cbyte, rt + chunk * 1024);
      }
      __syncthreads();
#pragma unroll
      for (int ks = 0; ks < 2; ++ks) {
        bf16x8 af[4], bg[4];
        const int kb = ks * 64 + rq * 16;
#pragma unroll
        for (int m = 0; m < 4; ++m) {
          int row = wr * 64 + m * 16 + lx;
          af[m] = *(const bf16x8*)(lt + row * 128 + (kb ^ swzk));
        }
#pragma unroll
        for (int n = 0; n < 4; ++n) {
          int row = wc * 64 + n * 16 + lx;
          bg[n] = *(const bf16x8*)(rt + row * 128 + (kb ^ swzk));
        }
#pragma unroll
        for (int m = 0; m < 4; ++m)
#pragma unroll
          for (int n = 0; n < 4; ++n)
            acc[m][n] = __builtin_amdgcn_mfma_f32_16x16x32_bf16(af[m], bg[n], acc[m][n], 0, 0, 0);
      }
      __syncthreads();
    }

    const float c0 = 640.0f;   // (D/2)/T
    const float c1 = 2.5f;     // 0.25/T
    float aR[4][4];
#pragma unroll
    for (int m = 0; m < 4; ++m)
#pragma unroll
      for (int v = 0; v < 4; ++v)
        aR[m][v] = a[rowBase + wr * 64 + m * 16 + rq * 4 + v];
    float aC[4];
#pragma unroll
    for (int n = 0; n < 4; ++n) aC[n] = a[colBase + wc * 64 + n * 16 + lx];

    // pass 1: acc -> S
#pragma unroll
    for (int m = 0; m < 4; ++m)
#pragma unroll
      for (int n = 0; n < 4; ++n)
#pragma unroll
        for (int v = 0; v < 4; ++v) {
          int grow = rowBase + wr * 64 + m * 16 + rq * 4 + v;
          int gcol = colBase + wc * 64 + n * 16 + lx;
          float S = c0 - c1 * (acc[m][n][v] + aR[m][v] + aC[n]);
          if (gcol == grow) {
            S = -INFINITY;
          } else if (gcol == (grow ^ B_HALF)) {
            S += to_add;
            pos[grow] = S;   // S symmetric: also row gcol's positive
            pos[gcol] = S;
          }
          acc[m][n][v] = S;
        }

    // pass 2: row partials -> lsep[row][cb]
#pragma unroll
    for (int m = 0; m < 4; ++m)
#pragma unroll
      for (int v = 0; v < 4; ++v) {
        float pm = -INFINITY;
#pragma unroll
        for (int n = 0; n < 4; ++n) pm = fmaxf(pm, acc[m][n][v]);
#pragma unroll
        for (int x = 1; x < 16; x <<= 1) pm = fmaxf(pm, __shfl_xor(pm, x));
        float ps = 0.f;
#pragma unroll
        for (int n = 0; n < 4; ++n) ps += __expf(acc[m][n][v] - pm);
#pragma unroll
        for (int x = 1; x < 16; x <<= 1) ps += __shfl_xor(ps, x);
        if (lx == 0) red[wr * 64 + m * 16 + rq * 4 + v][wc] = make_float2(pm, ps);
      }
    __syncthreads();
    if (tid < 128) {
      float2 p0 = red[tid][0], p1 = red[tid][1];
      float M = fmaxf(p0.x, p1.x);
      float S = p0.y * __expf(p0.x - M) + p1.y * __expf(p1.x - M);
      lsep[(size_t)(rowBase + tid) * NGRP + cb] = M + logf(S);
    }

    // pass 3: column partials -> lsep[col][rb]  (off-diagonal tiles only)
    if (rb != cb) {
      __syncthreads();
#pragma unroll
      for (int n = 0; n < 4; ++n) {
        float cm = -INFINITY;
#pragma unroll
        for (int m = 0; m < 4; ++m)
#pragma unroll
          for (int v = 0; v < 4; ++v) cm = fmaxf(cm, acc[m][n][v]);
        cm = fmaxf(cm, __shfl_xor(cm, 16));
        cm = fmaxf(cm, __shfl_xor(cm, 32));
        float cs = 0.f;
#pragma unroll
        for (int m = 0; m < 4; ++m)
#pragma unroll
          for (int v = 0; v < 4; ++v) cs += __expf(acc[m][n][v] - cm);
        cs += __shfl_xor(cs, 16);
        cs += __shfl_xor(cs, 32);
        if (lane < 16) red[wc * 64 + n * 16 + lane][wr] = make_float2(cm, cs);
      }
      __syncthreads();
      if (tid < 128) {
        float2 p0 = red[tid][0], p1 = red[tid][1];
        float M = fmaxf(p0.x, p1.x);
        float S = p0.y * __expf(p0.x - M) + p1.y * __expf(p1.x - M);
        lsep[(size_t)(colBase + tid) * NGRP + rb] = M + logf(S);
      }
    }
  }

  grid_barrier(1);

  // =========== P2: per-row LSE -> 512 block partials ===========
  if (bid < 512) {
    int row = bid * 8 + (tid >> 5);   // 8 rows x 32 lanes
    int g = tid & 31;
    float mv = lsep[(size_t)row * NGRP + g];
    float M = mv;
#pragma unroll
    for (int x = 1; x < 32; x <<= 1) M = fmaxf(M, __shfl_xor(M, x));
    float s = __expf(mv - M);
#pragma unroll
    for (int x = 1; x < 32; x <<= 1) s += __shfl_xor(s, x);
    float contrib = (M + logf(s)) - pos[row];
    if (g == 0) rp8[tid >> 5] = contrib;
    __syncthreads();
    if (tid == 0) {
      float t = 0.f;
#pragma unroll
      for (int i = 0; i < 8; ++i) t += rp8[i];
      partial[bid] = t;
    }
  }

  grid_barrier(2);

  // =========== P3: final sum (block 0, fixed order) ===========
  if (bid == 0) {
    fr[tid] = partial[tid] + partial[tid + 256];
    __syncthreads();
#pragma unroll
    for (int off = 128; off > 0; off >>= 1) {
      if (tid < off) fr[tid] += fr[tid + off];
      __syncthreads();
    }
    if (tid == 0) out[0] = fr[0] * (1.0f / 4096.0f);
  }
}

// ===========================================================================
extern "C" void kernel_launch(void* const* d_in, const int* in_sizes, int n_in,
                              void* d_out, int out_size, void* d_ws, size_t ws_size,
                              hipStream_t stream) {
  const float* mu_x    = (const float*)d_in[1];
  const float* sigma_x = (const float*)d_in[2];
  const float* mu_p    = (const float*)d_in[3];
  const float* sigma_p = (const float*)d_in[4];
  float* out = (float*)d_out;

  float to_add = (float)(-log((4095.0 - 1.0 / 5.0) / 4094.0));

  const size_t featB = (size_t)N_TOT * K_DIM * 2;   // 4 MB each
  char* ws = (char*)d_ws;
  __hip_bfloat16* Lf = (__hip_bfloat16*)(ws);
  __hip_bfloat16* Rf = (__hip_bfloat16*)(ws + featB);
  float* a       = (float*)(ws + 2 * featB);                     // 16 KB
  float* lsep    = (float*)(ws + 2 * featB + 16384);             // 512 KB
  float* pos     = (float*)(ws + 2 * featB + 16384 + 524288);    // 16 KB
  float* partial = (float*)(ws + 2 * featB + 16384 + 524288 + 16384);  // 2 KB

  fused_all<<<dim3(NBLK), dim3(256), 0, stream>>>(
      mu_x, sigma_x, mu_p, sigma_p, Lf, Rf, a, lsep, pos, partial, out, to_add);
}